// Round 2
// baseline (327.802 us; speedup 1.0000x reference)
//
#include <hip/hip_runtime.h>
#include <math.h>

// Problem constants (reference: B=32, P=256, D=64, T=4096, SCALE=1)
#define Bb 32
#define Pp 256
#define Dd 64
#define Tt 4096

// kernel1: one wave per (batch, 64-task chunk). 64 chunks/batch x 32 b -> 2048 waves.
// Each lane owns one task; its W column (64 fp32) is PINNED in VGPRs via the
// empty-asm trick (R1 showed the compiler otherwise re-loads it every p:
// 8.6 GB of L2 traffic -> 230 us, L2-BW-bound).
// ws layout: float4 (m, s, v, pad) at [((b*P + p)*64 + chunk)]  -> 8.4 MB.
__global__ __launch_bounds__(256) void k_scan(const float* __restrict__ data,
                                              const float* __restrict__ targets,
                                              const float* __restrict__ task_pool,
                                              float4* __restrict__ ws) {
  const int b     = blockIdx.x >> 4;          // 16 blocks per batch
  const int wid   = threadIdx.x >> 6;
  const int lane  = threadIdx.x & 63;
  const int chunk = ((blockIdx.x & 15) << 2) | wid;   // 0..63
  const int t     = (chunk << 6) | lane;              // this lane's task

  // W column for task t: load once, pin in VGPRs.
  float w[Dd];
#pragma unroll
  for (int d = 0; d < Dd; d += 4) {
    const float4 r = *(const float4*)(task_pool + (size_t)t * Dd + d);
    w[d] = r.x; w[d + 1] = r.y; w[d + 2] = r.z; w[d + 3] = r.w;
  }
#pragma unroll
  for (int d = 0; d < Dd; ++d) asm volatile("" : "+v"(w[d]));  // forbid remat/sink

  const float* __restrict__ drow = data + (size_t)b * (Pp * Dd);  // wave-uniform base
  const float* __restrict__ tgt  = targets + b * Pp;
  float4* __restrict__ wsb       = ws + (size_t)b * (Pp * 64);

  float c = 0.f;  // cumulative score (loglik prefix) for this lane's task
#pragma unroll 2
  for (int p = 0; p < Pp; ++p) {
    // pred = data[b,p,:] . W[:,t]; data row is wave-uniform -> scalar loads.
    // 4 independent accumulators break the 64-deep FMA dependence chain.
    float a0 = 0.f, a1 = 0.f, a2 = 0.f, a3 = 0.f;
    const float* __restrict__ r = drow + p * Dd;
#pragma unroll
    for (int d = 0; d < Dd; d += 4) {
      a0 = fmaf(r[d],     w[d],     a0);
      a1 = fmaf(r[d + 1], w[d + 1], a1);
      a2 = fmaf(r[d + 2], w[d + 2], a2);
      a3 = fmaf(r[d + 3], w[d + 3], a3);
    }
    const float pred = (a0 + a1) + (a2 + a3);

    // posterior over this chunk uses c (= prefix through p-1; p=0 -> uniform)
    float m = c;
#pragma unroll
    for (int off = 32; off; off >>= 1) m = fmaxf(m, __shfl_xor(m, off, 64));
    const float e = __expf(c - m);   // <= 1 (scores <= 0), no overflow
    float s = e, v = e * pred;
#pragma unroll
    for (int off = 32; off; off >>= 1) {
      s += __shfl_xor(s, off, 64);
      v += __shfl_xor(v, off, 64);
    }
    if (lane == 0) wsb[p * 64 + chunk] = make_float4(m, s, v, 0.f);

    // score update AFTER emitting the prefix posterior (log_norm const drops out)
    const float err = tgt[p] - pred;
    c = fmaf(-0.5f * err, err, c);
  }
}

// kernel2: one wave per (b,p); exact merge of the 64 chunk triples.
// value represented by a triple is e^m * (s, v); merge with global shift M.
__global__ __launch_bounds__(256) void k_merge(const float4* __restrict__ ws,
                                               float* __restrict__ out) {
  const int gt   = blockIdx.x * 256 + threadIdx.x;
  const int bp   = gt >> 6;   // b*P + p
  const int lane = gt & 63;   // chunk id
  const float4 o = ws[(size_t)bp * 64 + lane];
  const float m = o.x, s = o.y, v = o.z;
  float M = m;
#pragma unroll
  for (int off = 32; off; off >>= 1) M = fmaxf(M, __shfl_xor(M, off, 64));
  const float f = __expf(m - M);
  float S = f * s, V = f * v;
#pragma unroll
  for (int off = 32; off; off >>= 1) {
    S += __shfl_xor(S, off, 64);
    V += __shfl_xor(V, off, 64);
  }
  if (lane == 0) out[bp] = V / S;
}

extern "C" void kernel_launch(void* const* d_in, const int* in_sizes, int n_in,
                              void* d_out, int out_size, void* d_ws, size_t ws_size,
                              hipStream_t stream) {
  const float* data      = (const float*)d_in[0];
  const float* targets   = (const float*)d_in[1];
  const float* task_pool = (const float*)d_in[2];
  float* out = (float*)d_out;
  float4* ws = (float4*)d_ws;  // needs 32*256*64*16 B = 8.4 MB

  k_scan<<<dim3(512), dim3(256), 0, stream>>>(data, targets, task_pool, ws);
  k_merge<<<dim3((Bb * Pp * 64) / 256), dim3(256), 0, stream>>>(ws, out);
}

// Round 4
// 324.084 us; speedup vs baseline: 1.0115x; 1.0115x over previous
//
#include <hip/hip_runtime.h>
#include <math.h>

// Problem constants (reference: B=32, P=256, D=64, T=4096, SCALE=1)
#define Bb 32
#define Pp 256
#define Dd 64
#define Tt 4096

// kernel1: one wave per (batch, 64-task chunk). 64 chunks/batch x 32 b -> 2048
// waves = exactly 2 waves/SIMD. __launch_bounds__(256, 2) raises the VGPR cap
// to 256/lane so the per-lane W column (64 fp32) stays register-resident.
//   R1 (default bounds): ~40 VGPR cap -> W re-fetched from L2 every p -> 230 us.
//   R2 (asm pin, default bounds): W spilled to scratch -> 275 us.
//   R3 (stale softmax shift): NaN — scores drop ~32/step, e^{c-m} flushed to 0
//       for ALL lanes within ~3 steps of a refresh -> S=0 -> V/S NaN. The
//       per-step exact max guarantees e=1 at the argmax lane (s>=1): REQUIRED.
// ws layout: float4 (m, s, v, pad) at [((b*P + p)*64 + chunk)] -> 8.4 MB.
__global__ __launch_bounds__(256, 2) void k_scan(const float* __restrict__ data,
                                                 const float* __restrict__ targets,
                                                 const float* __restrict__ task_pool,
                                                 float4* __restrict__ ws) {
  const int b     = blockIdx.x >> 4;          // 16 blocks per batch
  const int wid   = threadIdx.x >> 6;
  const int lane  = threadIdx.x & 63;
  const int chunk = ((blockIdx.x & 15) << 2) | wid;   // 0..63
  const int t     = (chunk << 6) | lane;              // this lane's task

  // W column for task t: load once; with the (256,2) budget it stays in VGPRs.
  float w[Dd];
#pragma unroll
  for (int d = 0; d < Dd; d += 4) {
    const float4 r = *(const float4*)(task_pool + (size_t)t * Dd + d);
    w[d] = r.x; w[d + 1] = r.y; w[d + 2] = r.z; w[d + 3] = r.w;
  }
#pragma unroll
  for (int d = 0; d < Dd; ++d) asm volatile("" : "+v"(w[d]));  // forbid remat/sink

  const float* __restrict__ drow = data + (size_t)b * (Pp * Dd);  // wave-uniform
  const float* __restrict__ tgt  = targets + b * Pp;
  float4* __restrict__ wsb       = ws + (size_t)b * (Pp * 64);

  float c = 0.f;  // cumulative score (loglik prefix) for this lane's task
#pragma unroll 2
  for (int p = 0; p < Pp; ++p) {
    // pred = data[b,p,:] . W[:,t]; row address is wave-uniform -> scalar loads.
    float a0 = 0.f, a1 = 0.f, a2 = 0.f, a3 = 0.f;
    const float* __restrict__ r = drow + p * Dd;
#pragma unroll
    for (int d = 0; d < Dd; d += 4) {
      a0 = fmaf(r[d],     w[d],     a0);
      a1 = fmaf(r[d + 1], w[d + 1], a1);
      a2 = fmaf(r[d + 2], w[d + 2], a2);
      a3 = fmaf(r[d + 3], w[d + 3], a3);
    }
    const float pred = (a0 + a1) + (a2 + a3);

    // exact per-step wave max of c: guarantees e=1 at the argmax lane (no
    // all-lane underflow; see R3 post-mortem). Uses prefix through p-1.
    float m = c;
#pragma unroll
    for (int off = 32; off; off >>= 1) m = fmaxf(m, __shfl_xor(m, off, 64));
    const float e = __expf(c - m);   // in (0,1], ==1 at the max lane
    float s = e, v = e * pred;
#pragma unroll
    for (int off = 32; off; off >>= 1) {
      s += __shfl_xor(s, off, 64);
      v += __shfl_xor(v, off, 64);
    }
    if (lane == 0) wsb[p * 64 + chunk] = make_float4(m, s, v, 0.f);

    // score update AFTER emitting the prefix posterior (log_norm const drops out)
    const float err = tgt[p] - pred;
    c = fmaf(-0.5f * err, err, c);
  }
}

// kernel2: one wave per (b,p); exact merge of the 64 chunk triples.
// value represented by a triple is e^m * (s, v); merge with global shift M.
__global__ __launch_bounds__(256) void k_merge(const float4* __restrict__ ws,
                                               float* __restrict__ out) {
  const int gt   = blockIdx.x * 256 + threadIdx.x;
  const int bp   = gt >> 6;   // b*P + p
  const int lane = gt & 63;   // chunk id
  const float4 o = ws[(size_t)bp * 64 + lane];
  const float m = o.x, s = o.y, v = o.z;
  float M = m;
#pragma unroll
  for (int off = 32; off; off >>= 1) M = fmaxf(M, __shfl_xor(M, off, 64));
  const float f = __expf(m - M);
  float S = f * s, V = f * v;
#pragma unroll
  for (int off = 32; off; off >>= 1) {
    S += __shfl_xor(S, off, 64);
    V += __shfl_xor(V, off, 64);
  }
  if (lane == 0) out[bp] = V / S;
}

extern "C" void kernel_launch(void* const* d_in, const int* in_sizes, int n_in,
                              void* d_out, int out_size, void* d_ws, size_t ws_size,
                              hipStream_t stream) {
  const float* data      = (const float*)d_in[0];
  const float* targets   = (const float*)d_in[1];
  const float* task_pool = (const float*)d_in[2];
  float* out = (float*)d_out;
  float4* ws = (float4*)d_ws;  // needs 32*256*64*16 B = 8.4 MB

  k_scan<<<dim3(512), dim3(256), 0, stream>>>(data, targets, task_pool, ws);
  k_merge<<<dim3((Bb * Pp * 64) / 256), dim3(256), 0, stream>>>(ws, out);
}